// Round 7
// baseline (1679.250 us; speedup 1.0000x reference)
//
#include <hip/hip_runtime.h>
#include <math.h>

typedef double f64x4 __attribute__((ext_vector_type(4)));

#define B_ 128
#define T_ 200
#define D_ 784
#define H_ 500
#define O_ 10
#define N_ROWS 25600          // B_*T_
#define BD 100352             // B_*D_
#define BH 64000              // B_*H_
#define DECAY_M 0.77880078307140487f

// workspace layout (bytes)
#define OFF_BUFC   80281600ULL                 // 25600*784*4
#define OFF_BUFE   131481600ULL                // + 25600*500*4
#define OFF_STATS  132505600ULL                // + 25600*10*4
#define OFF_FLAGS  132518144ULL                // + 1568*8
#define WS_REQUIRED 132518272ULL

// ===========================================================================
// fp64-MFMA GEMM: C[N,M] = A[N,K] * W[M,K]^T + bias[M]
// 64x64 tile, BK=16, 256 threads (4 waves as 2x2, each wave 32x32).
// Double-buffered LDS, single barrier per k-tile (stage k+1 loads issued
// before MFMA block, ds_write after -> HBM latency hides under ~1024cy MFMA).
// LDS fp32, stride 72, SWIZZLED column: element (k,row) stored at
//   col = (row + 16*((k>>2)&1)) & 63
// -> staging writes 2-way (free), MFMA reads 2-way (free). [bank math in log]
// v_mfma_f64_16x16x4 verified mappings (round-5 HW probe):
//   A: lane l -> (row=l&15, k=l>>4)   B: lane l -> (col=l&15, k=l>>4)
//   C/D: lane l, acc q -> row = 4*q + (l>>4), col = l&15     [H1-corrected]
// ===========================================================================
__global__ __launch_bounds__(256) void gemm_mfma(
    const float* __restrict__ A, const float* __restrict__ W,
    const float* __restrict__ bias, float* __restrict__ C,
    int N, int K, int M) {
  __shared__ float As[2][16][72];
  __shared__ float Bs[2][16][72];
  const int tid = threadIdx.x;
  const int lane = tid & 63;
  const int wave = tid >> 6;
  const int wr = (wave >> 1) * 32;
  const int wc = (wave & 1) * 32;
  const int l15 = lane & 15, lk = lane >> 4;
  const int n0 = blockIdx.y * 64;
  const int m0 = blockIdx.x * 64;

  f64x4 acc[2][2];
#pragma unroll
  for (int i = 0; i < 2; ++i)
#pragma unroll
    for (int j = 0; j < 2; ++j) acc[i][j] = f64x4{0.0, 0.0, 0.0, 0.0};

  // staging assignment: thread -> (row=srow, k=sk4..sk4+3), float4 global
  const int srow = tid >> 2;
  const int sk4 = (tid & 3) << 2;
  const int colW = (srow + ((tid & 1) << 4)) & 63;   // (k>>2)&1 == tid&1
  // read-column LUTs [i][k-parity]
  int ca[2][2], cb[2][2];
#pragma unroll
  for (int i = 0; i < 2; ++i) {
    int ra = wr + i * 16 + l15, rb = wc + i * 16 + l15;
    ca[i][0] = ra; ca[i][1] = (ra + 16) & 63;
    cb[i][0] = rb; cb[i][1] = (rb + 16) & 63;
  }

  const float* Arow = A + (size_t)(n0 + srow) * K;
  const float* Wrow = W + (size_t)(m0 + srow) * K;
  const bool wok = (m0 + srow) < M;
  const int Kt = (K + 15) >> 4;

  // prologue: stage tile 0
  {
    float4 va = make_float4(0.f, 0.f, 0.f, 0.f), vb = va;
    if (sk4 + 3 < K) va = *(const float4*)(Arow + sk4);
    if (wok && sk4 + 3 < K) vb = *(const float4*)(Wrow + sk4);
    As[0][sk4 + 0][colW] = va.x; As[0][sk4 + 1][colW] = va.y;
    As[0][sk4 + 2][colW] = va.z; As[0][sk4 + 3][colW] = va.w;
    Bs[0][sk4 + 0][colW] = vb.x; Bs[0][sk4 + 1][colW] = vb.y;
    Bs[0][sk4 + 2][colW] = vb.z; Bs[0][sk4 + 3][colW] = vb.w;
  }
  __syncthreads();

  for (int kt = 0; kt < Kt; ++kt) {
    const int cur = kt & 1;
    const bool more = (kt + 1) < Kt;
    float4 va = make_float4(0.f, 0.f, 0.f, 0.f), vb = va;
    if (more) {
      int gc = ((kt + 1) << 4) + sk4;
      if (gc + 3 < K) va = *(const float4*)(Arow + gc);
      if (wok && gc + 3 < K) vb = *(const float4*)(Wrow + gc);
    }
    double af[2][4], bf[2][4];
#pragma unroll
    for (int ks = 0; ks < 4; ++ks) {
      int kr = ks * 4 + lk, p = ks & 1;
#pragma unroll
      for (int i = 0; i < 2; ++i) {
        af[i][ks] = (double)As[cur][kr][ca[i][p]];
        bf[i][ks] = (double)Bs[cur][kr][cb[i][p]];
      }
    }
#pragma unroll
    for (int ks = 0; ks < 4; ++ks)
#pragma unroll
      for (int i = 0; i < 2; ++i)
#pragma unroll
        for (int j = 0; j < 2; ++j)
          acc[i][j] = __builtin_amdgcn_mfma_f64_16x16x4f64(
              af[i][ks], bf[j][ks], acc[i][j], 0, 0, 0);
    if (more) {
      int nb = cur ^ 1;
      As[nb][sk4 + 0][colW] = va.x; As[nb][sk4 + 1][colW] = va.y;
      As[nb][sk4 + 2][colW] = va.z; As[nb][sk4 + 3][colW] = va.w;
      Bs[nb][sk4 + 0][colW] = vb.x; Bs[nb][sk4 + 1][colW] = vb.y;
      Bs[nb][sk4 + 2][colW] = vb.z; Bs[nb][sk4 + 3][colW] = vb.w;
    }
    __syncthreads();
  }
#pragma unroll
  for (int i = 0; i < 2; ++i)
#pragma unroll
    for (int j = 0; j < 2; ++j)
#pragma unroll
      for (int q = 0; q < 4; ++q) {
        int n = n0 + wr + i * 16 + q * 4 + lk;       // H1-corrected row
        int m = m0 + wc + j * 16 + l15;
        if (m < M) C[(size_t)n * M + m] = (float)(acc[i][j][q] + (double)bias[m]);
      }
}

// ---------------------------------------------------------------------------
// GEMM1 (fp64 MFMA, dbuf+swizzle): A[n][k] = X[b*(D*T) + k*T + t], n = b*T+t;
// output permuted to [T][B][D].
// ---------------------------------------------------------------------------
__global__ __launch_bounds__(256) void gemm1_mfma(
    const float* __restrict__ X, const float* __restrict__ W,
    const float* __restrict__ bias, float* __restrict__ C) {
  __shared__ float As[2][16][72];
  __shared__ float Bs[2][16][72];
  const int tid = threadIdx.x;
  const int lane = tid & 63;
  const int wave = tid >> 6;
  const int wr = (wave >> 1) * 32;
  const int wc = (wave & 1) * 32;
  const int l15 = lane & 15, lk = lane >> 4;
  const int n0 = blockIdx.y * 64;
  const int m0 = blockIdx.x * 64;

  f64x4 acc[2][2];
#pragma unroll
  for (int i = 0; i < 2; ++i)
#pragma unroll
    for (int j = 0; j < 2; ++j) acc[i][j] = f64x4{0.0, 0.0, 0.0, 0.0};

  // A staging: thread -> (row=arow, k=kq*4..kq*4+3), scalar strided loads
  const int arow = tid & 63;
  const int kq = tid >> 6;
  const int colWA = (arow + ((kq & 1) << 4)) & 63;
  const int gr = n0 + arow;
  const int bb = gr / T_;
  const int tt = gr - bb * T_;
  const float* Abase = X + (size_t)bb * (D_ * T_) + tt;
  // B staging: float4 per thread
  const int srow = tid >> 2;
  const int sk4 = (tid & 3) << 2;
  const int colWB = (srow + ((tid & 1) << 4)) & 63;
  const float* Wrow = W + (size_t)(m0 + srow) * D_;
  const bool wok = (m0 + srow) < D_;

  int ca[2][2], cb[2][2];
#pragma unroll
  for (int i = 0; i < 2; ++i) {
    int ra = wr + i * 16 + l15, rb = wc + i * 16 + l15;
    ca[i][0] = ra; ca[i][1] = (ra + 16) & 63;
    cb[i][0] = rb; cb[i][1] = (rb + 16) & 63;
  }

  // prologue: stage tile 0
  {
    float4 vb = make_float4(0.f, 0.f, 0.f, 0.f);
    if (wok) vb = *(const float4*)(Wrow + sk4);
#pragma unroll
    for (int u = 0; u < 4; ++u)
      As[0][kq * 4 + u][colWA] = Abase[(size_t)(kq * 4 + u) * T_];
    Bs[0][sk4 + 0][colWB] = vb.x; Bs[0][sk4 + 1][colWB] = vb.y;
    Bs[0][sk4 + 2][colWB] = vb.z; Bs[0][sk4 + 3][colWB] = vb.w;
  }
  __syncthreads();

  for (int kt = 0; kt < D_ / 16; ++kt) {
    const int cur = kt & 1;
    const bool more = (kt + 1) < D_ / 16;
    float va[4];
    float4 vb = make_float4(0.f, 0.f, 0.f, 0.f);
    if (more) {
      int k0 = (kt + 1) << 4;
#pragma unroll
      for (int u = 0; u < 4; ++u)
        va[u] = Abase[(size_t)(k0 + kq * 4 + u) * T_];
      if (wok) vb = *(const float4*)(Wrow + k0 + sk4);
    }
    double af[2][4], bf[2][4];
#pragma unroll
    for (int ks = 0; ks < 4; ++ks) {
      int kr = ks * 4 + lk, p = ks & 1;
#pragma unroll
      for (int i = 0; i < 2; ++i) {
        af[i][ks] = (double)As[cur][kr][ca[i][p]];
        bf[i][ks] = (double)Bs[cur][kr][cb[i][p]];
      }
    }
#pragma unroll
    for (int ks = 0; ks < 4; ++ks)
#pragma unroll
      for (int i = 0; i < 2; ++i)
#pragma unroll
        for (int j = 0; j < 2; ++j)
          acc[i][j] = __builtin_amdgcn_mfma_f64_16x16x4f64(
              af[i][ks], bf[j][ks], acc[i][j], 0, 0, 0);
    if (more) {
      int nb = cur ^ 1;
#pragma unroll
      for (int u = 0; u < 4; ++u) As[nb][kq * 4 + u][colWA] = va[u];
      Bs[nb][sk4 + 0][colWB] = vb.x; Bs[nb][sk4 + 1][colWB] = vb.y;
      Bs[nb][sk4 + 2][colWB] = vb.z; Bs[nb][sk4 + 3][colWB] = vb.w;
    }
    __syncthreads();
  }
#pragma unroll
  for (int i = 0; i < 2; ++i)
#pragma unroll
    for (int j = 0; j < 2; ++j)
#pragma unroll
      for (int q = 0; q < 4; ++q) {
        int n = n0 + wr + i * 16 + q * 4 + lk;       // H1-corrected row
        int rb = n / T_;
        int rt = n - rb * T_;
        int m = m0 + wc + j * 16 + l15;
        if (m < D_)
          C[((size_t)rt * B_ + rb) * D_ + m] = (float)(acc[i][j][q] + (double)bias[m]);
      }
}

// ===========================================================================
// Scans (proven)
// ===========================================================================
__global__ __launch_bounds__(256) void bn_stats(const float* __restrict__ Y,
                                                double* __restrict__ stats) {
  int col = blockIdx.x * 256 + threadIdx.x;
  int r0 = blockIdx.y * 256;
  if (col >= D_) return;
  double s = 0.0, s2 = 0.0;
  for (int rr = 0; rr < 256; ++rr) {
    float v = Y[(size_t)(r0 + rr) * D_ + col];
    s += v;
    s2 += (double)v * v;
  }
  atomicAdd(&stats[col], s);
  atomicAdd(&stats[D_ + col], s2);
}

__global__ __launch_bounds__(256) void bn_axon(
    float* __restrict__ Y, const double* __restrict__ stats,
    const float* __restrict__ gamma, const float* __restrict__ beta,
    const float* __restrict__ a1, const float* __restrict__ a2) {
  int j = blockIdx.x * 256 + threadIdx.x;
  int d = j % D_;
  double mean = stats[d] * (1.0 / N_ROWS);
  double var = stats[D_ + d] * (1.0 / N_ROWS) - mean * mean;
  float rstd = (float)(1.0 / sqrt(var + 1e-5));
  float mf = (float)mean;
  float g = gamma[d], be = beta[d];
  float c1 = a1[d], c2 = a2[d];
  float p1 = 0.f, p2 = 0.f;
  for (int t = 0; t < T_; ++t) {
    float x = Y[(size_t)t * BD + j];
    x = g * (x - mf) * rstd + be;
    x = 1.f / (1.f + expf(-x));
    float psp = c1 * p1 + c2 * p2 + x;
    Y[(size_t)t * BD + j] = psp;
    p2 = p1;
    p1 = psp;
  }
}

__global__ __launch_bounds__(256) void lif_axon(
    float* __restrict__ Z, const float* __restrict__ mask,
    const float* __restrict__ a1, const float* __restrict__ a2) {
  int j = blockIdx.x * 256 + threadIdx.x;
  int o = j % H_;
  float c1 = a1[o], c2 = a2[o];
  const float* mrow = mask + (size_t)j * T_;
  float v = 0.f, s = 0.f, p1 = 0.f, p2 = 0.f;
  for (int t = 0; t < T_; ++t) {
    float z = Z[(size_t)t * BH + j];
    v = DECAY_M * v * (1.f - s) + z;
    s = (v > 1.f) ? 1.f : 0.f;
    float sm = s * mrow[t];
    float psp = c1 * p1 + c2 * p2 + sm;
    Z[(size_t)t * BH + j] = psp;
    p2 = p1;
    p1 = psp;
  }
}

__global__ __launch_bounds__(256) void lif_out(const float* __restrict__ Z,
                                               float* __restrict__ out) {
  int j = blockIdx.x * 256 + threadIdx.x;
  if (j >= B_ * O_) return;
  float v = 0.f, s = 0.f;
  for (int t = 0; t < T_; ++t) {
    float z = Z[(size_t)t * (B_ * O_) + j];
    v = DECAY_M * v * (1.f - s) + z;
    s = (v > 1.f) ? 1.f : 0.f;
    out[(size_t)j * T_ + t] = s;
  }
}

// ===========================================================================
// Probes -> flags in ws; merged into out AFTER lif_out (survive clobbering).
// ===========================================================================
__global__ void probe_ws(unsigned long long ws, float* flags) {
  if (ws < WS_REQUIRED) flags[0] = 9.0e6f;
}

__global__ __launch_bounds__(256) void probe_dot(
    const float* __restrict__ a, int sa, const float* __restrict__ w,
    const float* __restrict__ bias, const float* __restrict__ got,
    float sentinel, float* flags, int slot, int K) {
  __shared__ float red[256];
  float s = 0.f;
  for (int k = threadIdx.x; k < K; k += 256)
    s = fmaf(a[(size_t)k * sa], w[k], s);
  red[threadIdx.x] = s;
  __syncthreads();
  for (int h = 128; h > 0; h >>= 1) {
    if (threadIdx.x < h) red[threadIdx.x] += red[threadIdx.x + h];
    __syncthreads();
  }
  if (threadIdx.x == 0) {
    float want = red[0] + *bias;
    if (!(fabsf(*got - want) < 1e-2f)) flags[slot] = sentinel;
  }
}

__global__ void merge_flags(const float* __restrict__ flags, float* out) {
  int i = threadIdx.x;  // 16
  float f = flags[i];
  if (f != 0.0f) out[i] = f;
}

extern "C" void kernel_launch(void* const* d_in, const int* in_sizes, int n_in,
                              void* d_out, int out_size, void* d_ws, size_t ws_size,
                              hipStream_t stream) {
  const float* inputs = (const float*)d_in[0];
  const float* W_mlp  = (const float*)d_in[1];
  const float* b_mlp  = (const float*)d_in[2];
  const float* gamma  = (const float*)d_in[3];
  const float* beta   = (const float*)d_in[4];
  const float* a1_1   = (const float*)d_in[5];
  const float* a2_1   = (const float*)d_in[6];
  const float* W1     = (const float*)d_in[7];
  const float* b1     = (const float*)d_in[8];
  const float* a1_2   = (const float*)d_in[9];
  const float* a2_2   = (const float*)d_in[10];
  const float* W2     = (const float*)d_in[11];
  const float* b2     = (const float*)d_in[12];
  const float* a1_3   = (const float*)d_in[13];
  const float* a2_3   = (const float*)d_in[14];
  const float* W3     = (const float*)d_in[15];
  const float* b3     = (const float*)d_in[16];
  const float* mask1  = (const float*)d_in[17];
  const float* mask2  = (const float*)d_in[18];

  char* ws = (char*)d_ws;
  float* bufB  = (float*)ws;                  // y1 -> h1 -> z2 -> h3
  float* bufC  = (float*)(ws + OFF_BUFC);     // z1 -> h2
  float* bufE  = (float*)(ws + OFF_BUFE);     // z3
  double* stats = (double*)(ws + OFF_STATS);
  float* flags = (float*)(ws + OFF_FLAGS);
  float* out = (float*)d_out;

  hipMemsetAsync(flags, 0, 64, stream);
  hipMemsetAsync(stats, 0, D_ * 2 * sizeof(double), stream);

  // Layer 0: shared linear -> [T][B][D]
  gemm1_mfma<<<dim3(13, 400), 256, 0, stream>>>(inputs, W_mlp, b_mlp, bufB);
  probe_dot<<<1, 256, 0, stream>>>(inputs + 11 * (D_ * T_) + 37, T_,
                                   W_mlp + 123 * D_, b_mlp + 123,
                                   bufB + (size_t)(37 * B_ + 11) * D_ + 123,
                                   8.0e6f, flags, 1, D_);

  bn_stats<<<dim3(4, 100), 256, 0, stream>>>(bufB, stats);
  bn_axon<<<BD / 256, 256, 0, stream>>>(bufB, stats, gamma, beta, a1_1, a2_1);

  // Layer 1
  gemm_mfma<<<dim3(8, 400), 256, 0, stream>>>(bufB, W1, b1, bufC, N_ROWS, D_, H_);
  probe_dot<<<1, 256, 0, stream>>>(bufB + (size_t)(91 * B_ + 77) * D_, 1,
                                   W1 + 333 * D_, b1 + 333,
                                   bufC + (size_t)(91 * B_ + 77) * H_ + 333,
                                   5.0e6f, flags, 3, D_);
  lif_axon<<<BH / 256, 256, 0, stream>>>(bufC, mask1, a1_2, a2_2);

  // Layer 2
  gemm_mfma<<<dim3(8, 400), 256, 0, stream>>>(bufC, W2, b2, bufB, N_ROWS, H_, H_);
  probe_dot<<<1, 256, 0, stream>>>(bufC + (size_t)(123 * B_ + 45) * H_, 1,
                                   W2 + 87 * H_, b2 + 87,
                                   bufB + (size_t)(123 * B_ + 45) * H_ + 87,
                                   3.0e6f, flags, 6, H_);
  lif_axon<<<BH / 256, 256, 0, stream>>>(bufB, mask2, a1_3, a2_3);

  // Layer 3
  gemm_mfma<<<dim3(1, 400), 256, 0, stream>>>(bufB, W3, b3, bufE, N_ROWS, H_, O_);
  probe_dot<<<1, 256, 0, stream>>>(bufB + (size_t)(11 * B_ + 99) * H_, 1,
                                   W3 + 7 * H_, b3 + 7,
                                   bufE + (size_t)(11 * B_ + 99) * O_ + 7,
                                   2.0e6f, flags, 7, H_);
  lif_out<<<5, 256, 0, stream>>>(bufE, out);

  probe_ws<<<1, 1, 0, stream>>>((unsigned long long)ws_size, flags);
  merge_flags<<<1, 16, 0, stream>>>(flags, out);
}